// Round 2
// 185.584 us; speedup vs baseline: 1.0883x; 1.0883x over previous
//
#include <hip/hip_runtime.h>
#include <math.h>

#define BATCH 64
#define CC    256
#define ATTRN 300
#define DD    256
#define HW    784
#define HW4   196   // HW / 4
#define O1    32
#define TF4   49    // float4 columns per tile (4 tiles * 49 * 4 = 784)

// ws layout (floats):
// [0, 16384)             : sx    [64][256]
// [16384, 16384+524288)  : corrT [64][256 t][32 o]   (t-major, o contiguous)

// ---------------------------------------------------------------- k1
__global__ __launch_bounds__(256) void k1_emb_sketch(
    const float* __restrict__ attr_one_hot,
    const float* __restrict__ W_emb,
    const float* __restrict__ b_emb,
    const int*   __restrict__ h1,
    const float* __restrict__ s1,
    float* __restrict__ sx)
{
    const int b = blockIdx.x, t = threadIdx.x;
    __shared__ float s_attr[ATTRN];
    __shared__ float s_W[256 * 36];
    __shared__ float s_sx[DD];

    s_attr[t] = attr_one_hot[b * ATTRN + t];
    if (t < ATTRN - 256) s_attr[256 + t] = attr_one_hot[b * ATTRN + 256 + t];
    s_sx[t] = 0.f;

    float acc = b_emb[t];
    for (int a0 = 0; a0 < ATTRN; a0 += 32) {
        __syncthreads();
        const int ncol = (ATTRN - a0) < 32 ? (ATTRN - a0) : 32;
        const int nf4 = ncol >> 2;
        for (int i = t; i < 256 * nf4; i += 256) {
            int r = i / nf4, v = i - r * nf4;
            float4 w = *(const float4*)(W_emb + r * ATTRN + a0 + 4 * v);
            *(float4*)(&s_W[r * 36 + 4 * v]) = w;
        }
        __syncthreads();
        for (int v = 0; v < nf4; ++v) {
            float4 wv = *(const float4*)(&s_W[t * 36 + 4 * v]);
            float4 av = *(const float4*)(&s_attr[a0 + 4 * v]);
            acc += av.x * wv.x + av.y * wv.y + av.z * wv.z + av.w * wv.w;
        }
    }
    __syncthreads();
    atomicAdd(&s_sx[h1[t]], acc * s1[t]);
    __syncthreads();
    sx[b * DD + t] = s_sx[t];
}

// ---------------------------------------------------------------- k2
// corrT[b][t][o] = sum_k conv1_w[o][k] * sx[b][(k-t)&255]
__global__ __launch_bounds__(256) void k2_corr(
    const float* __restrict__ sx,
    const float* __restrict__ conv1_w,
    float* __restrict__ corrT)
{
    const int b = blockIdx.x, og = blockIdx.y, t = threadIdx.x;
    const int o0 = og * 8;
    __shared__ float s_sx[DD];
    __shared__ float s_w1[8][DD];
    __shared__ float s_c[8][DD];

    s_sx[t] = sx[b * DD + t];
#pragma unroll
    for (int j = 0; j < 8; ++j) s_w1[j][t] = conv1_w[(o0 + j) * CC + t];
    __syncthreads();

    float acc[8] = {0.f,0.f,0.f,0.f,0.f,0.f,0.f,0.f};
    for (int k4 = 0; k4 < 64; ++k4) {
        const int k = k4 * 4;
        float x0 = s_sx[(k     - t) & 255];
        float x1 = s_sx[(k + 1 - t) & 255];
        float x2 = s_sx[(k + 2 - t) & 255];
        float x3 = s_sx[(k + 3 - t) & 255];
#pragma unroll
        for (int oo = 0; oo < 8; ++oo) {
            float4 w = *(const float4*)&s_w1[oo][k];
            acc[oo] += w.x * x0 + w.y * x1 + w.z * x2 + w.w * x3;
        }
    }
#pragma unroll
    for (int oo = 0; oo < 8; ++oo) s_c[oo][t] = acc[oo];
    __syncthreads();

    float4 r0, r1;
    r0.x = s_c[0][t]; r0.y = s_c[1][t]; r0.z = s_c[2][t]; r0.w = s_c[3][t];
    r1.x = s_c[4][t]; r1.y = s_c[5][t]; r1.z = s_c[6][t]; r1.w = s_c[7][t];
    float4* dst = (float4*)(corrT + ((size_t)b * DD + t) * O1 + o0);
    dst[0] = r0; dst[1] = r1;
}

// ---------------------------------------------------------------- k3
// 1024 threads = 16 waves: 4-way c-split (ci) x 4-way o-octet split (oi).
// Each wave: 64 c-iters, 1 global float4 + 2 broadcast ds_read_b128 + 32 FMA
// into acc[8] (one o-octet x 4 spatial). 4-way cross-wave reduce per octet
// (same partition & order as before -> bitwise-identical results).
// Pl (pitch 36, 36KB) aliased with the reduce buffer (28KB) via union:
// Pl is dead once the first reduce barrier passes.
#define FMA4(A, S, E) { (A).x += (S)*(E).x; (A).y += (S)*(E).y; (A).z += (S)*(E).z; (A).w += (S)*(E).w; }

__global__ __launch_bounds__(1024, 4) void k3_main(
    const float* __restrict__ ent,
    const float* __restrict__ corrT,
    const int*   __restrict__ h2,
    const float* __restrict__ s2,
    const float* __restrict__ conv2_w,
    float* __restrict__ out_map,
    float* __restrict__ out_feat)
{
    const int b = blockIdx.x, tile = blockIdx.y;
    const int tid  = threadIdx.x;
    const int wv   = tid >> 6, lane = tid & 63;
    const int ci   = wv >> 2;     // c-split: c in [64*ci, 64*ci+64)
    const int oi   = wv & 3;      // o-octet: o in [8*oi, 8*oi+8)

    union SMem {
        float  Pl[CC][36];          // P[c][o], pitch 36 floats (bank spread)
        float4 red[4][TF4][9];      // [ci][f4 loc][8 acc + 1 pad]
    };
    __shared__ SMem sm;
    __shared__ float4 s_amap4[TF4];
    __shared__ float  s_c2[O1];

    // ---- stage P[c][o] = s2[c] * corrT[b][h2[c]][o]; 4 threads per c
    {
        const int c = tid >> 2, qp = tid & 3;   // qp -> float4 pair 2qp, 2qp+1
        const int hc = h2[c];
        const float sc = s2[c];
        const float4* src = (const float4*)(corrT + ((size_t)b * DD + hc) * O1);
        float4 x0 = src[2 * qp], x1 = src[2 * qp + 1];
        x0.x *= sc; x0.y *= sc; x0.z *= sc; x0.w *= sc;
        x1.x *= sc; x1.y *= sc; x1.z *= sc; x1.w *= sc;
        *(float4*)&sm.Pl[c][8 * qp]     = x0;
        *(float4*)&sm.Pl[c][8 * qp + 4] = x1;
        if (tid < O1) s_c2[tid] = conv2_w[tid];
    }
    __syncthreads();

    const bool act = lane < TF4;
    const int f4i = tile * TF4 + (act ? lane : TF4 - 1);
    const float4* ent4 = (const float4*)ent;
    const int c0 = ci * 64;

    float4 acc[8];
#pragma unroll
    for (int o = 0; o < 8; ++o) acc[o] = make_float4(0.f, 0.f, 0.f, 0.f);

    const float4* eptr = ent4 + (size_t)(b * CC + c0) * HW4 + f4i;
#pragma unroll 4
    for (int cc = 0; cc < 64; ++cc) {
        const int c = c0 + cc;
        float4 e4 = eptr[(size_t)cc * HW4];
        float4 pa = *(const float4*)&sm.Pl[c][8 * oi];
        float4 pb = *(const float4*)&sm.Pl[c][8 * oi + 4];
        FMA4(acc[0], pa.x, e4); FMA4(acc[1], pa.y, e4);
        FMA4(acc[2], pa.z, e4); FMA4(acc[3], pa.w, e4);
        FMA4(acc[4], pb.x, e4); FMA4(acc[5], pb.y, e4);
        FMA4(acc[6], pb.z, e4); FMA4(acc[7], pb.w, e4);
    }

    // ---- cross-wave reduce + relu + conv2, one o-octet per pass
    float pre = 0.f;
#pragma unroll
    for (int g = 0; g < 4; ++g) {
        __syncthreads();                 // pass g-1 reads done; Pl dead after g=0 entry
        if (oi == g && act) {
#pragma unroll
            for (int i = 0; i < 8; ++i) sm.red[ci][lane][i] = acc[i];
        }
        __syncthreads();
        if (tid < 4 * TF4) {
            const int fi = tid >> 2, j = tid & 3;
#pragma unroll
            for (int i = 0; i < 8; ++i) {
                float v = ((const float*)&sm.red[0][fi][i])[j]
                        + ((const float*)&sm.red[1][fi][i])[j]
                        + ((const float*)&sm.red[2][fi][i])[j]
                        + ((const float*)&sm.red[3][fi][i])[j];
                pre += s_c2[8 * g + i] * fmaxf(v, 0.f);
            }
        }
    }
    __syncthreads();
    if (tid < 4 * TF4) {
        const int fi = tid >> 2, j = tid & 3;
        float am = 1.f / (1.f + expf(-pre));
        ((float*)&s_amap4[fi])[j] = am;
        out_map[b * HW + tile * (4 * TF4) + tid] = am;
    }
    __syncthreads();

    // ---- output pass: wave wv covers c in [16*wv, 16*wv+16) — nested inside
    // its GEMM read range [64*ci, 64*ci+64) so re-reads are L1/L2-warm.
    const float4 am4 = s_amap4[act ? lane : 0];
    float4* of4 = (float4*)out_feat;
    const int cb = wv * 16;
#pragma unroll 4
    for (int cc = 0; cc < 16; ++cc) {
        const int c = cb + cc;
        if (act) {
            const size_t idx = (size_t)(b * CC + c) * HW4 + f4i;
            float4 e4 = ent4[idx];
            float4 r;
            r.x = am4.x * e4.x; r.y = am4.y * e4.y;
            r.z = am4.z * e4.z; r.w = am4.w * e4.w;
            of4[idx] = r;
        }
    }
}

extern "C" void kernel_launch(void* const* d_in, const int* in_sizes, int n_in,
                              void* d_out, int out_size, void* d_ws, size_t ws_size,
                              hipStream_t stream) {
    const float* ent   = (const float*)d_in[0];
    const float* attr  = (const float*)d_in[1];
    const float* W_emb = (const float*)d_in[2];
    const float* b_emb = (const float*)d_in[3];
    const int*   h1    = (const int*)d_in[4];
    const float* s1    = (const float*)d_in[5];
    const int*   h2    = (const int*)d_in[6];
    const float* s2    = (const float*)d_in[7];
    const float* c1w   = (const float*)d_in[8];
    const float* c2w   = (const float*)d_in[9];

    float* ws    = (float*)d_ws;
    float* sx    = ws;
    float* corrT = ws + 16384;

    float* out      = (float*)d_out;
    float* out_map  = out;                 // [64,1,28,28]
    float* out_feat = out + BATCH * HW;    // [64,256,28,28]

    hipLaunchKernelGGL(k1_emb_sketch, dim3(BATCH), dim3(256), 0, stream,
                       attr, W_emb, b_emb, h1, s1, sx);
    hipLaunchKernelGGL(k2_corr, dim3(BATCH, 4), dim3(256), 0, stream,
                       sx, c1w, corrT);
    hipLaunchKernelGGL(k3_main, dim3(BATCH, 4), dim3(1024), 0, stream,
                       ent, corrT, h2, s2, c2w, out_map, out_feat);
}

// Round 3
// 169.549 us; speedup vs baseline: 1.1913x; 1.0946x over previous
//
#include <hip/hip_runtime.h>
#include <math.h>

#define BATCH 64
#define CC    256
#define ATTRN 300
#define DD    256
#define HW    784
#define HW4   196   // HW / 4
#define O1    32
#define TF4   49    // float4 columns per tile (4 tiles * 49 * 4 = 784)

// ws layout (floats):
// [0, 16384)             : emb   [64][256]
// [16384, 16384+524288)  : corrT [64][256 t][32 o]   (t-major, o contiguous)

// ---------------------------------------------------------------- k1
// emb[b][t] = b_emb[t] + sum_a attr[b][a] * W_emb[t][a]
// Grid (64 b, 4 q): block computes 64 rows. Each row = one 4-lane quad;
// chunks of 76/76/76/72 floats (all 16B-aligned), __shfl_xor quad reduce.
__global__ __launch_bounds__(256) void k1_emb(
    const float* __restrict__ attr_one_hot,
    const float* __restrict__ W_emb,
    const float* __restrict__ b_emb,
    float* __restrict__ emb)
{
    const int b = blockIdx.x, q = blockIdx.y, t = threadIdx.x;
    __shared__ float s_attr[ATTRN];

    if (t < 75) {
        float4 a = *(const float4*)(attr_one_hot + b * ATTRN + 4 * t);
        *(float4*)&s_attr[4 * t] = a;
    }
    __syncthreads();

    const int r  = t >> 2, j = t & 3;
    const int tr = q * 64 + r;
    const int a0 = j * 76;
    const int nf4 = (j == 3) ? 18 : 19;     // 72 or 76 floats, all float4
    const float* wr = W_emb + (size_t)tr * ATTRN + a0;

    float acc = 0.f;
    for (int v = 0; v < nf4; ++v) {
        float4 w = *(const float4*)(wr + 4 * v);
        float4 a = *(const float4*)(&s_attr[a0 + 4 * v]);
        acc += w.x * a.x + w.y * a.y + w.z * a.z + w.w * a.w;
    }
    acc += __shfl_xor(acc, 1);
    acc += __shfl_xor(acc, 2);
    if (j == 0) emb[b * CC + tr] = acc + b_emb[tr];
}

// ---------------------------------------------------------------- k2
// sketch: s_sx[d] = sum_{c: h1[c]=d} s1[c]*emb[b][c]   (LDS atomics)
// corrT[b][t][o] = sum_k conv1_w[o][k] * s_sx[(k-t)&255]
__global__ __launch_bounds__(256) void k2_corr(
    const float* __restrict__ emb,
    const int*   __restrict__ h1,
    const float* __restrict__ s1,
    const float* __restrict__ conv1_w,
    float* __restrict__ corrT)
{
    const int b = blockIdx.x, og = blockIdx.y, t = threadIdx.x;
    const int o0 = og * 8;
    __shared__ float s_sx[DD];
    __shared__ float s_w1[8][DD];
    __shared__ float s_c[8][DD];

    s_sx[t] = 0.f;
#pragma unroll
    for (int j = 0; j < 8; ++j) s_w1[j][t] = conv1_w[(o0 + j) * CC + t];
    __syncthreads();
    atomicAdd(&s_sx[h1[t]], s1[t] * emb[b * CC + t]);
    __syncthreads();

    float acc[8] = {0.f,0.f,0.f,0.f,0.f,0.f,0.f,0.f};
    for (int k4 = 0; k4 < 64; ++k4) {
        const int k = k4 * 4;
        float x0 = s_sx[(k     - t) & 255];
        float x1 = s_sx[(k + 1 - t) & 255];
        float x2 = s_sx[(k + 2 - t) & 255];
        float x3 = s_sx[(k + 3 - t) & 255];
#pragma unroll
        for (int oo = 0; oo < 8; ++oo) {
            float4 w = *(const float4*)&s_w1[oo][k];
            acc[oo] += w.x * x0 + w.y * x1 + w.z * x2 + w.w * x3;
        }
    }
#pragma unroll
    for (int oo = 0; oo < 8; ++oo) s_c[oo][t] = acc[oo];
    __syncthreads();

    float4 r0, r1;
    r0.x = s_c[0][t]; r0.y = s_c[1][t]; r0.z = s_c[2][t]; r0.w = s_c[3][t];
    r1.x = s_c[4][t]; r1.y = s_c[5][t]; r1.z = s_c[6][t]; r1.w = s_c[7][t];
    float4* dst = (float4*)(corrT + ((size_t)b * DD + t) * O1 + o0);
    dst[0] = r0; dst[1] = r1;
}

// ---------------------------------------------------------------- k3
// 1024 threads = 16 waves: 4-way c-split (ci) x 4-way o-octet split (oi).
// GEMM loop: batches of 8 global float4 loads issued before the 8x32 FMA
// block -> 8 loads in flight per thread (MLP to cover ~900cy HBM latency).
#define FMA4(A, S, E) { (A).x += (S)*(E).x; (A).y += (S)*(E).y; (A).z += (S)*(E).z; (A).w += (S)*(E).w; }

__global__ __launch_bounds__(1024, 4) void k3_main(
    const float* __restrict__ ent,
    const float* __restrict__ corrT,
    const int*   __restrict__ h2,
    const float* __restrict__ s2,
    const float* __restrict__ conv2_w,
    float* __restrict__ out_map,
    float* __restrict__ out_feat)
{
    const int b = blockIdx.x, tile = blockIdx.y;
    const int tid  = threadIdx.x;
    const int wv   = tid >> 6, lane = tid & 63;
    const int ci   = wv >> 2;     // c-split: c in [64*ci, 64*ci+64)
    const int oi   = wv & 3;      // o-octet: o in [8*oi, 8*oi+8)

    union SMem {
        float  Pl[CC][36];          // P[c][o], pitch 36 floats (bank spread)
        float4 red[4][TF4][9];      // [ci][f4 loc][8 acc + 1 pad]
    };
    __shared__ SMem sm;
    __shared__ float4 s_amap4[TF4];
    __shared__ float  s_c2[O1];

    // ---- stage P[c][o] = s2[c] * corrT[b][h2[c]][o]; 4 threads per c
    {
        const int c = tid >> 2, qp = tid & 3;
        const int hc = h2[c];
        const float sc = s2[c];
        const float4* src = (const float4*)(corrT + ((size_t)b * DD + hc) * O1);
        float4 x0 = src[2 * qp], x1 = src[2 * qp + 1];
        x0.x *= sc; x0.y *= sc; x0.z *= sc; x0.w *= sc;
        x1.x *= sc; x1.y *= sc; x1.z *= sc; x1.w *= sc;
        *(float4*)&sm.Pl[c][8 * qp]     = x0;
        *(float4*)&sm.Pl[c][8 * qp + 4] = x1;
        if (tid < O1) s_c2[tid] = conv2_w[tid];
    }
    __syncthreads();

    const bool act = lane < TF4;
    const int f4i = tile * TF4 + (act ? lane : TF4 - 1);
    const float4* ent4 = (const float4*)ent;
    const int c0 = ci * 64;

    float4 acc[8];
#pragma unroll
    for (int o = 0; o < 8; ++o) acc[o] = make_float4(0.f, 0.f, 0.f, 0.f);

    const float4* eptr = ent4 + (size_t)(b * CC + c0) * HW4 + f4i;
    for (int cc0 = 0; cc0 < 64; cc0 += 8) {
        float4 e[8];
#pragma unroll
        for (int u = 0; u < 8; ++u) {
            e[u] = eptr[(size_t)(cc0 + u) * HW4];
            asm volatile("" : "+v"(e[u].x), "+v"(e[u].y), "+v"(e[u].z), "+v"(e[u].w));
        }
#pragma unroll
        for (int u = 0; u < 8; ++u) {
            const int c = c0 + cc0 + u;
            float4 pa = *(const float4*)&sm.Pl[c][8 * oi];
            float4 pb = *(const float4*)&sm.Pl[c][8 * oi + 4];
            FMA4(acc[0], pa.x, e[u]); FMA4(acc[1], pa.y, e[u]);
            FMA4(acc[2], pa.z, e[u]); FMA4(acc[3], pa.w, e[u]);
            FMA4(acc[4], pb.x, e[u]); FMA4(acc[5], pb.y, e[u]);
            FMA4(acc[6], pb.z, e[u]); FMA4(acc[7], pb.w, e[u]);
        }
    }

    // ---- cross-wave reduce + relu + conv2, one o-octet per pass
    float pre = 0.f;
#pragma unroll
    for (int g = 0; g < 4; ++g) {
        __syncthreads();                 // Pl dead after g=0 entry
        if (oi == g && act) {
#pragma unroll
            for (int i = 0; i < 8; ++i) sm.red[ci][lane][i] = acc[i];
        }
        __syncthreads();
        if (tid < 4 * TF4) {
            const int fi = tid >> 2, j = tid & 3;
#pragma unroll
            for (int i = 0; i < 8; ++i) {
                float v = ((const float*)&sm.red[0][fi][i])[j]
                        + ((const float*)&sm.red[1][fi][i])[j]
                        + ((const float*)&sm.red[2][fi][i])[j]
                        + ((const float*)&sm.red[3][fi][i])[j];
                pre += s_c2[8 * g + i] * fmaxf(v, 0.f);
            }
        }
    }
    __syncthreads();
    if (tid < 4 * TF4) {
        const int fi = tid >> 2, j = tid & 3;
        float am = 1.f / (1.f + expf(-pre));
        ((float*)&s_amap4[fi])[j] = am;
        out_map[b * HW + tile * (4 * TF4) + tid] = am;
    }
    __syncthreads();

    // ---- output pass: wave wv covers c in [16*wv, 16*wv+16) — nested inside
    // its GEMM read range so re-reads are L1/L2-warm.
    const float4 am4 = s_amap4[act ? lane : 0];
    float4* of4 = (float4*)out_feat;
    const int cb = wv * 16;
#pragma unroll 4
    for (int cc = 0; cc < 16; ++cc) {
        const int c = cb + cc;
        if (act) {
            const size_t idx = (size_t)(b * CC + c) * HW4 + f4i;
            float4 e4 = ent4[idx];
            float4 r;
            r.x = am4.x * e4.x; r.y = am4.y * e4.y;
            r.z = am4.z * e4.z; r.w = am4.w * e4.w;
            of4[idx] = r;
        }
    }
}

extern "C" void kernel_launch(void* const* d_in, const int* in_sizes, int n_in,
                              void* d_out, int out_size, void* d_ws, size_t ws_size,
                              hipStream_t stream) {
    const float* ent   = (const float*)d_in[0];
    const float* attr  = (const float*)d_in[1];
    const float* W_emb = (const float*)d_in[2];
    const float* b_emb = (const float*)d_in[3];
    const int*   h1    = (const int*)d_in[4];
    const float* s1    = (const float*)d_in[5];
    const int*   h2    = (const int*)d_in[6];
    const float* s2    = (const float*)d_in[7];
    const float* c1w   = (const float*)d_in[8];
    const float* c2w   = (const float*)d_in[9];

    float* ws    = (float*)d_ws;
    float* emb   = ws;
    float* corrT = ws + 16384;

    float* out      = (float*)d_out;
    float* out_map  = out;                 // [64,1,28,28]
    float* out_feat = out + BATCH * HW;    // [64,256,28,28]

    hipLaunchKernelGGL(k1_emb, dim3(BATCH, 4), dim3(256), 0, stream,
                       attr, W_emb, b_emb, emb);
    hipLaunchKernelGGL(k2_corr, dim3(BATCH, 4), dim3(256), 0, stream,
                       emb, h1, s1, c1w, corrT);
    hipLaunchKernelGGL(k3_main, dim3(BATCH, 4), dim3(1024), 0, stream,
                       ent, corrT, h2, s2, c2w, out_map, out_feat);
}

// Round 5
// 156.920 us; speedup vs baseline: 1.2871x; 1.0805x over previous
//
#include <hip/hip_runtime.h>
#include <math.h>

#define BATCH 64
#define CC    256
#define ATTRN 300
#define DD    256
#define HW    784
#define HW4   196   // HW / 4
#define O1    32
#define TF4   49    // float4 columns per tile (4 tiles * 49 * 4 = 784)

// ws layout (floats):
// [16384, 16384+524288)  : corrT [64][256 t][32 o]   (t-major, o contiguous)

// ---------------------------------------------------------------- k2 (fused k1+sketch+circulant)
// Phase A (waves 0-3): emb[c] = b_emb[c] + dot(attr[b,:], W_emb[c,:]);
//                      sketch s_sx[h1[c]] += s1[c]*emb[c]   (LDS atomics)
//          (waves 4-7): stage w1 octet into LDS (overlapped)
// Phase B: corrT[b][t][o] = sum_k w1[o][k] * s_sx[(k-t)&255], k-sum split
//          across the two half-blocks (kh=0: k<128, kh=1: k>=128).
__global__ __launch_bounds__(512) void k2_fused(
    const float* __restrict__ attr_one_hot,
    const float* __restrict__ W_emb,
    const float* __restrict__ b_emb,
    const int*   __restrict__ h1,
    const float* __restrict__ s1,
    const float* __restrict__ conv1_w,
    float* __restrict__ corrT)
{
    const int b = blockIdx.x, og = blockIdx.y;
    const int tid = threadIdx.x;
    const int t = tid & 255, kh = tid >> 8;   // kh is wave-uniform
    const int o0 = og * 8;

    __shared__ float s_attr[ATTRN];
    __shared__ float s_sx[DD];
    __shared__ float s_w1[8][DD];
    __shared__ float s_part[8][DD];

    if (kh == 0) {
        s_sx[t] = 0.f;
        if (t < 75) {
            float4 a = *(const float4*)(attr_one_hot + b * ATTRN + 4 * t);
            *(float4*)&s_attr[4 * t] = a;
        }
    } else {
#pragma unroll
        for (int j = 0; j < 8; ++j) s_w1[j][t] = conv1_w[(o0 + j) * CC + t];
    }
    __syncthreads();

    if (kh == 0) {
        float acc = b_emb[t];
        const float* wr = W_emb + (size_t)t * ATTRN;   // rows are 1200B = 16B-aligned
#pragma unroll 5
        for (int v = 0; v < 75; ++v) {
            float4 w = *(const float4*)(wr + 4 * v);
            float4 a = *(const float4*)(&s_attr[4 * v]);
            acc += w.x * a.x + w.y * a.y + w.z * a.z + w.w * a.w;
        }
        atomicAdd(&s_sx[h1[t]], s1[t] * acc);
    }
    __syncthreads();

    float acc[8] = {0.f,0.f,0.f,0.f,0.f,0.f,0.f,0.f};
    const int kbase = kh << 7;
    for (int k4 = 0; k4 < 32; ++k4) {
        const int k = kbase + 4 * k4;
        float x0 = s_sx[(k     - t) & 255];
        float x1 = s_sx[(k + 1 - t) & 255];
        float x2 = s_sx[(k + 2 - t) & 255];
        float x3 = s_sx[(k + 3 - t) & 255];
#pragma unroll
        for (int oo = 0; oo < 8; ++oo) {
            float4 w = *(const float4*)&s_w1[oo][k];
            acc[oo] += w.x * x0 + w.y * x1 + w.z * x2 + w.w * x3;
        }
    }
    if (kh == 1) {
#pragma unroll
        for (int oo = 0; oo < 8; ++oo) s_part[oo][t] = acc[oo];
    }
    __syncthreads();
    if (kh == 0) {
        float4 r0, r1;
        r0.x = acc[0] + s_part[0][t]; r0.y = acc[1] + s_part[1][t];
        r0.z = acc[2] + s_part[2][t]; r0.w = acc[3] + s_part[3][t];
        r1.x = acc[4] + s_part[4][t]; r1.y = acc[5] + s_part[5][t];
        r1.z = acc[6] + s_part[6][t]; r1.w = acc[7] + s_part[7][t];
        float4* dst = (float4*)(corrT + ((size_t)b * DD + t) * O1 + o0);
        dst[0] = r0; dst[1] = r1;
    }
}

// ---------------------------------------------------------------- k3
// 1024 threads = 16 waves: 4-way c-split (ci) x 4-way o-octet split (oi).
// GEMM loop: proven round-2 form (unroll 4, compiler-batched loads).
#define FMA4(A, S, E) { (A).x += (S)*(E).x; (A).y += (S)*(E).y; (A).z += (S)*(E).z; (A).w += (S)*(E).w; }

__global__ __launch_bounds__(1024, 4) void k3_main(
    const float* __restrict__ ent,
    const float* __restrict__ corrT,
    const int*   __restrict__ h2,
    const float* __restrict__ s2,
    const float* __restrict__ conv2_w,
    float* __restrict__ out_map,
    float* __restrict__ out_feat)
{
    const int b = blockIdx.x, tile = blockIdx.y;
    const int tid  = threadIdx.x;
    const int wv   = tid >> 6, lane = tid & 63;
    const int ci   = wv >> 2;     // c-split: c in [64*ci, 64*ci+64)
    const int oi   = wv & 3;      // o-octet: o in [8*oi, 8*oi+8)

    union SMem {
        float  Pl[CC][36];          // P[c][o], pitch 36 floats (bank spread)
        float4 red[4][TF4][9];      // [ci][f4 loc][8 acc + 1 pad]
    };
    __shared__ SMem sm;
    __shared__ float4 s_amap4[TF4];
    __shared__ float  s_c2[O1];

    // ---- stage P[c][o] = s2[c] * corrT[b][h2[c]][o]; 4 threads per c
    {
        const int c = tid >> 2, qp = tid & 3;
        const int hc = h2[c];
        const float sc = s2[c];
        const float4* src = (const float4*)(corrT + ((size_t)b * DD + hc) * O1);
        float4 x0 = src[2 * qp], x1 = src[2 * qp + 1];
        x0.x *= sc; x0.y *= sc; x0.z *= sc; x0.w *= sc;
        x1.x *= sc; x1.y *= sc; x1.z *= sc; x1.w *= sc;
        *(float4*)&sm.Pl[c][8 * qp]     = x0;
        *(float4*)&sm.Pl[c][8 * qp + 4] = x1;
        if (tid < O1) s_c2[tid] = conv2_w[tid];
    }
    __syncthreads();

    const bool act = lane < TF4;
    const int f4i = tile * TF4 + (act ? lane : TF4 - 1);
    const float4* ent4 = (const float4*)ent;
    const int c0 = ci * 64;

    float4 acc[8];
#pragma unroll
    for (int o = 0; o < 8; ++o) acc[o] = make_float4(0.f, 0.f, 0.f, 0.f);

    const float4* eptr = ent4 + (size_t)(b * CC + c0) * HW4 + f4i;
#pragma unroll 4
    for (int cc = 0; cc < 64; ++cc) {
        const int c = c0 + cc;
        float4 e4 = eptr[(size_t)cc * HW4];
        float4 pa = *(const float4*)&sm.Pl[c][8 * oi];
        float4 pb = *(const float4*)&sm.Pl[c][8 * oi + 4];
        FMA4(acc[0], pa.x, e4); FMA4(acc[1], pa.y, e4);
        FMA4(acc[2], pa.z, e4); FMA4(acc[3], pa.w, e4);
        FMA4(acc[4], pb.x, e4); FMA4(acc[5], pb.y, e4);
        FMA4(acc[6], pb.z, e4); FMA4(acc[7], pb.w, e4);
    }

    // ---- cross-wave reduce + relu + conv2, one o-octet per pass
    float pre = 0.f;
#pragma unroll
    for (int g = 0; g < 4; ++g) {
        __syncthreads();                 // Pl dead after g=0 entry
        if (oi == g && act) {
#pragma unroll
            for (int i = 0; i < 8; ++i) sm.red[ci][lane][i] = acc[i];
        }
        __syncthreads();
        if (tid < 4 * TF4) {
            const int fi = tid >> 2, j = tid & 3;
#pragma unroll
            for (int i = 0; i < 8; ++i) {
                float v = ((const float*)&sm.red[0][fi][i])[j]
                        + ((const float*)&sm.red[1][fi][i])[j]
                        + ((const float*)&sm.red[2][fi][i])[j]
                        + ((const float*)&sm.red[3][fi][i])[j];
                pre += s_c2[8 * g + i] * fmaxf(v, 0.f);
            }
        }
    }
    __syncthreads();
    if (tid < 4 * TF4) {
        const int fi = tid >> 2, j = tid & 3;
        float am = 1.f / (1.f + expf(-pre));
        ((float*)&s_amap4[fi])[j] = am;
        out_map[b * HW + tile * (4 * TF4) + tid] = am;
    }
    __syncthreads();

    // ---- output pass: wave wv covers c in [16*wv, 16*wv+16) — nested inside
    // its GEMM read range so re-reads are L1/L2-warm.
    const float4 am4 = s_amap4[act ? lane : 0];
    float4* of4 = (float4*)out_feat;
    const int cb = wv * 16;
#pragma unroll 4
    for (int cc = 0; cc < 16; ++cc) {
        const int c = cb + cc;
        if (act) {
            const size_t idx = (size_t)(b * CC + c) * HW4 + f4i;
            float4 e4 = ent4[idx];
            float4 r;
            r.x = am4.x * e4.x; r.y = am4.y * e4.y;
            r.z = am4.z * e4.z; r.w = am4.w * e4.w;
            of4[idx] = r;
        }
    }
}

extern "C" void kernel_launch(void* const* d_in, const int* in_sizes, int n_in,
                              void* d_out, int out_size, void* d_ws, size_t ws_size,
                              hipStream_t stream) {
    const float* ent   = (const float*)d_in[0];
    const float* attr  = (const float*)d_in[1];
    const float* W_emb = (const float*)d_in[2];
    const float* b_emb = (const float*)d_in[3];
    const int*   h1    = (const int*)d_in[4];
    const float* s1    = (const float*)d_in[5];
    const int*   h2    = (const int*)d_in[6];
    const float* s2    = (const float*)d_in[7];
    const float* c1w   = (const float*)d_in[8];
    const float* c2w   = (const float*)d_in[9];

    float* ws    = (float*)d_ws;
    float* corrT = ws + 16384;

    float* out      = (float*)d_out;
    float* out_map  = out;                 // [64,1,28,28]
    float* out_feat = out + BATCH * HW;    // [64,256,28,28]

    hipLaunchKernelGGL(k2_fused, dim3(BATCH, 4), dim3(512), 0, stream,
                       attr, W_emb, b_emb, h1, s1, c1w, corrT);
    hipLaunchKernelGGL(k3_main, dim3(BATCH, 4), dim3(1024), 0, stream,
                       ent, corrT, h2, s2, c2w, out_map, out_feat);
}